// Round 9
// baseline (290.104 us; speedup 1.0000x reference)
//
#include <hip/hip_runtime.h>

typedef unsigned short u16;
typedef unsigned int   u32;
typedef __bf16 bf16x8 __attribute__((ext_vector_type(8)));
typedef float  f32x4  __attribute__((ext_vector_type(4)));

#define DD 1024

__device__ __forceinline__ u16 f2bf(float f) {
  u32 u = __float_as_uint(f);
  u32 r = (u + 0x7FFFu + ((u >> 16) & 1u)) >> 16;
  return (u16)r;
}

// async global->LDS, 16B per lane. Dest must be wave-uniform-base + lane*16.
typedef const __attribute__((address_space(1))) void* gp1;
typedef __attribute__((address_space(3))) void* lp3;
__device__ __forceinline__ void gll16(const void* g, void* l) {
  __builtin_amdgcn_global_load_lds((gp1)g, (lp3)l, 16, 0, 0);
}

// ---------------------------------------------------------------------------
// kA: heavy pre-work only (ISOLATION SPLIT — round-8's merged k01m hid which
// phase owns the ~87us pole; this round attributes it).
// blocks 0..63  : AWBW[16][1024] = {A,B}@W_base partials (atomics, memset'd)
// blocks 64..67 : Mbuf: 4 Gram 8x8
// blocks 68..71 : Pb[32][1024] = bf16([Ao;Bo;Us;Ul])
// blocks 72..327: Wt[n][k] = bf16(W[k][n]) transpose
// No signals — kernel boundary orders AWBW for kC's RwT pack.
// ---------------------------------------------------------------------------
__global__ __launch_bounds__(256) void kA_heavy(
    const float* __restrict__ W,
    const float* __restrict__ Ao, const float* __restrict__ Bo,
    const float* __restrict__ Us, const float* __restrict__ Ul,
    float* __restrict__ AWBW, float* __restrict__ Mbuf,
    u16* __restrict__ Pb, u16* __restrict__ Wt) {
  __shared__ __align__(16) char shb[16384];   // union: red2 | red | T
  const int tid = threadIdx.x;
  const int bid = blockIdx.x;
  if (bid < 64) {
    float (*red2)[128][16] = (float (*)[128][16])shb;   // 16384 B
    const int m = bid;
    const int n = (m & 7) * 128 + (tid & 127), q = m >> 3, ih = tid >> 7;
    float acc[16];
#pragma unroll
    for (int k = 0; k < 16; k++) acc[k] = 0.f;
    const int ib = q * 128 + ih * 64;
    for (int i = ib; i < ib + 64; i++) {
      float wv = W[(long)i * DD + n];
#pragma unroll
      for (int k = 0; k < 8; k++) {
        acc[k]     += Ao[k * DD + i] * wv;
        acc[k + 8] += Bo[k * DD + i] * wv;
      }
    }
#pragma unroll
    for (int k = 0; k < 16; k++) red2[ih][tid & 127][k] = acc[k];
    __syncthreads();
    if (ih == 0)
#pragma unroll
      for (int k = 0; k < 16; k++)
        atomicAdd(&AWBW[k * DD + n], red2[0][tid][k] + red2[1][tid][k]);
  } else if (bid < 68) {
    float (*red)[4] = (float (*)[4])shb;                // 1024 B
    const int m = bid - 64;
    const float* L  = (m == 0 || m == 2) ? Ao : Bo;
    const float* Rr = (m < 2) ? Us : Ul;
    const int o = tid >> 2, ch = tid & 3;
    const int k = o >> 3, kp = o & 7;
    float a = 0.f;
    for (int i = ch * 256; i < ch * 256 + 256; i++)
      a += L[(long)k * DD + i] * Rr[(long)kp * DD + i];
    red[o][ch] = a;
    __syncthreads();
    if (tid < 64) Mbuf[m * 64 + tid] = red[tid][0] + red[tid][1] + red[tid][2] + red[tid][3];
  } else if (bid < 72) {
    const int m = bid - 68;
    const float* src = m == 0 ? Ao : m == 1 ? Bo : m == 2 ? Us : Ul;
#pragma unroll
    for (int j = 0; j < 8; j++)
      for (int q = 0; q < 4; q++) {
        int i = q * 256 + tid;
        Pb[(m * 8 + j) * DD + i] = f2bf(src[j * DD + i]);
      }
  } else {
    u16 (*T)[66] = (u16 (*)[66])shb;                    // 8448 B
    const int t = bid - 72, tr = t >> 4, tc = t & 15;
#pragma unroll
    for (int q2 = 0; q2 < 16; q2++) {
      int idx = q2 * 256 + tid, r = idx >> 6, c = idx & 63;
      T[r][c] = f2bf(W[(long)(tr * 64 + r) * DD + tc * 64 + c]);
    }
    __syncthreads();
#pragma unroll
    for (int q2 = 0; q2 < 16; q2++) {
      int idx = q2 * 256 + tid, c = idx >> 6, r = idx & 63;
      Wt[(long)(tc * 64 + c) * DD + tr * 64 + r] = T[r][c];
    }
  }
}

// ---------------------------------------------------------------------------
// kB: streamer only. 1024 blocks x 16 rows, ZERO LDS, no signals ->
// 4 blocks/CU = 16 waves/CU (2x round-8's TLP). Plain loop (asm pin proved
// useless in r8: VGPR 40, dur unchanged). XCD row-swizzle kept for k3b's
// warm-L2 handoff. If this stays ~85us the floor is external.
// ---------------------------------------------------------------------------
template <bool XB>
__global__ __launch_bounds__(256) void kB_stream(
    const float* __restrict__ x, u16* __restrict__ xb,
    float* __restrict__ pooled) {
  const int i = blockIdx.x;
  const int xcd = i & 7, local = i >> 3;     // local 0..127
  const int rb = xcd * 128 + local;          // row-block 0..1023 (16 rows ea)
  const int b = rb >> 8;
  const long r0 = (long)rb * 16;
  const int c0 = threadIdx.x * 4;
  float s0 = 0.f, s1 = 0.f, s2 = 0.f, s3 = 0.f;
  for (int r = 0; r < 16; r++) {
    float4 v = *(const float4*)(x + (r0 + r) * DD + c0);
    if (XB) {
      ushort4 o;
      o.x = f2bf(v.x); o.y = f2bf(v.y); o.z = f2bf(v.z); o.w = f2bf(v.w);
      *(ushort4*)(xb + (r0 + r) * DD + c0) = o;
    }
    s0 += v.x; s1 += v.y; s2 += v.z; s3 += v.w;
  }
  atomicAdd(&pooled[b * DD + c0 + 0], s0);
  atomicAdd(&pooled[b * DD + c0 + 1], s1);
  atomicAdd(&pooled[b * DD + c0 + 2], s2);
  atomicAdd(&pooled[b * DD + c0 + 3], s3);
}

// ---------------------------------------------------------------------------
// k2ab: conditioner chain (round-7 proven version; pooled/AWBW complete at
// kernel entry, only the internal h1pre->gates spin remains).
// blocks 0..31 : h1pre partials, then signal counter.
// blocks 32..35: spin until counter==32, then gates[b][24].
// blocks 36..39: pack RwT[n][32].
// ---------------------------------------------------------------------------
__global__ __launch_bounds__(256) void k2ab(
    const float* __restrict__ pooledsum,
    const float* __restrict__ lng, const float* __restrict__ lnb,
    const float* __restrict__ Wc1, float* __restrict__ h1pre,
    const float* __restrict__ AWBW, const float* Vs, const float* Vl,
    const float* bc1, const float* Wc2, const float* bc2,
    const float* Wrg, const float* brg, const float* Wrc, const float* brc,
    const float* Wsg, const float* bsg, const float* Wlc, const float* blc,
    float* __restrict__ gates, u16* __restrict__ RwT,
    u32* __restrict__ cnt) {
  const int tid = threadIdx.x;
  if (blockIdx.x < 32) {
    __shared__ float zs[1024];
    __shared__ float red[256];
    const int b = blockIdx.x >> 3, ch = blockIdx.x & 7;
    float4 v = *(const float4*)(pooledsum + b * DD + tid * 4);
    v.x *= (1.f / 4096.f); v.y *= (1.f / 4096.f); v.z *= (1.f / 4096.f); v.w *= (1.f / 4096.f);
    float s = v.x + v.y + v.z + v.w;
    float sq = v.x * v.x + v.y * v.y + v.z * v.z + v.w * v.w;
    red[tid] = s; __syncthreads();
    for (int st = 128; st > 0; st >>= 1) { if (tid < st) red[tid] += red[tid + st]; __syncthreads(); }
    float mu = red[0] * (1.f / 1024.f);
    __syncthreads();
    red[tid] = sq; __syncthreads();
    for (int st = 128; st > 0; st >>= 1) { if (tid < st) red[tid] += red[tid + st]; __syncthreads(); }
    float var = red[0] * (1.f / 1024.f) - mu * mu;
    float rs = rsqrtf(var + 1e-5f);
    __syncthreads();
    {
      float4 g = *(const float4*)(lng + tid * 4);
      float4 be = *(const float4*)(lnb + tid * 4);
      zs[tid * 4 + 0] = (v.x - mu) * rs * g.x + be.x;
      zs[tid * 4 + 1] = (v.y - mu) * rs * g.y + be.y;
      zs[tid * 4 + 2] = (v.z - mu) * rs * g.z + be.z;
      zs[tid * 4 + 3] = (v.w - mu) * rs * g.w + be.w;
    }
    __syncthreads();
    const int j = tid & 127, half = tid >> 7;
    float a = 0.f;
#pragma unroll 8
    for (int dd = 0; dd < 64; dd++) {
      int ldi = half * 64 + dd;
      a += zs[ch * 128 + ldi] * Wc1[(long)ch * 16384 + ldi * 128 + j];
    }
    red[tid] = a;
    __syncthreads();
    if (tid < 128) atomicAdd(&h1pre[b * 128 + tid], red[tid] + red[tid + 128]);
    __syncthreads();
    if (tid == 0) atomicAdd(cnt, 1u);
  } else if (blockIdx.x < 36) {
    __shared__ float h1s[128], hb[128];
    __shared__ float red[256];
    const int b = (int)blockIdx.x - 32;
    if (tid == 0) {
      while (atomicAdd(cnt, 0u) < 32u) __builtin_amdgcn_s_sleep(8);
    }
    __syncthreads();
    if (tid < 128) {
      float hv = atomicAdd(&h1pre[b * 128 + tid], 0.f) + bc1[tid];
      float th = tanhf(0.7978845608028654f * (hv + 0.044715f * hv * hv * hv));
      h1s[tid] = 0.5f * hv * (1.f + th);
    }
    __syncthreads();
    const int i = tid & 127, half = tid >> 7;
    float a = 0.f;
#pragma unroll 8
    for (int k = 0; k < 64; k++) {
      int kk = half * 64 + k;
      a += h1s[kk] * Wc2[kk * 128 + i];
    }
    red[tid] = a;
    __syncthreads();
    if (tid < 128) hb[tid] = red[tid] + red[tid + 128] + bc2[tid];
    __syncthreads();
    if (tid < 25) {
      float acc;
      if (tid == 0) {
        acc = brg[0];
        for (int k = 0; k < 128; k++) acc += hb[k] * Wrg[k];
        red[0] = 1.f / (1.f + expf(-acc));
      } else if (tid < 9) {
        int ci = tid - 1; acc = brc[ci];
        for (int k = 0; k < 128; k++) acc += hb[k] * Wrc[k * 8 + ci];
        red[tid] = tanhf(acc);
      } else if (tid < 17) {
        int ci = tid - 9; acc = bsg[ci];
        for (int k = 0; k < 128; k++) acc += hb[k] * Wsg[k * 8 + ci];
        red[tid] = tanhf(acc);
      } else {
        int ci = tid - 17; acc = blc[ci];
        for (int k = 0; k < 128; k++) acc += hb[k] * Wlc[k * 8 + ci];
        red[tid] = tanhf(acc);
      }
    }
    __syncthreads();
    if (tid < 24) {
      float g = red[0];
      gates[b * 32 + tid] = (tid < 8) ? g * red[1 + tid] : red[1 + tid];
    }
  } else {
    const int n = (int)(blockIdx.x - 36) * 256 + tid;
#pragma unroll
    for (int j = 0; j < 8; j++) {
      RwT[n * 32 + j]      = f2bf(AWBW[j * DD + n]);
      RwT[n * 32 + 8 + j]  = f2bf(AWBW[(8 + j) * DD + n]);
      RwT[n * 32 + 16 + j] = f2bf(Vs[(long)j * DD + n]);
      RwT[n * 32 + 24 + j] = f2bf(Vl[(long)j * DD + n]);
    }
  }
}

// ---------------------------------------------------------------------------
// k3b (mode A): fused GEMM, 128x256 tile, 512 blocks @ 2 blocks/CU.
// Double-buffered gll16, one barrier/chunk, XCD-bijective swizzle.
// (unchanged — steady-state below top-5 since round 7)
// ---------------------------------------------------------------------------
__global__ __launch_bounds__(256, 2) void k3b_fused(
    const u16* __restrict__ xb, const u16* __restrict__ Wt,
    const u16* __restrict__ Pb, const float* __restrict__ gates,
    const float* __restrict__ Mbuf, const u16* __restrict__ RwT,
    const float* __restrict__ bb, float* __restrict__ out) {
  __shared__ __align__(16) char smem[54400];
  const int tid = threadIdx.x, lane = tid & 63, w = tid >> 6;
  const int quad = lane >> 4, lrow = lane & 15;
  const int g = blockIdx.x;
  const int xcd = g & 7, local = g >> 3;
  const int bm = xcd * 16 + (local >> 2);
  const int bn2 = local & 3;
  const long m0 = (long)bm * 128;
  const int n0 = bn2 * 256;
  const int batch = bm >> 5;
  float* Ml = (float*)(smem + 53248);
  float* gl = (float*)(smem + 54272);
  Ml[tid] = Mbuf[tid];
  if (tid < 24) gl[tid] = gates[batch * 32 + tid];
  const int mw = (w & 1) * 64, nw = (w >> 1) * 128;
  const int pc0 = (w >> 1) * 16;
  const int sr = lane >> 2, sc = (lane & 3) * 16;
  const char* xbp = (const char*)xb;
  const char* wtp = (const char*)Wt;
  const char* pbp = (const char*)Pb;
  const long aOff0 = (m0 + (long)w * 16 + sr) * 2048 + sc;
  const long aOff1 = aOff0 + 64 * 2048;
  const long bOff  = ((long)n0 + w * 16 + sr) * 2048 + sc;
  const long pOff  = ((long)w * 16 + sr) * 2048 + sc;
  const int d0 = w * 1024 + lane * 16;

  f32x4 acc[4][8] = {};
  f32x4 acc2[4] = {};

  gll16(xbp + aOff0, smem + d0);
  gll16(xbp + aOff1, smem + d0 + 4096);
#pragma unroll
  for (int seg = 0; seg < 4; seg++)
    gll16(wtp + bOff + (long)seg * 64 * 2048, smem + 16384 + seg * 4096 + d0);
  if (w < 2) gll16(pbp + pOff, smem + 49152 + d0);
  __syncthreads();

  int cur = 0;
  for (int kc = 0; kc < 32; kc++) {
    if (kc < 31) {
      const long ko = (long)(kc + 1) * 64;
      const int s = cur ^ 1;
      gll16(xbp + aOff0 + ko, smem + s * 8192 + d0);
      gll16(xbp + aOff1 + ko, smem + s * 8192 + d0 + 4096);
#pragma unroll
      for (int seg = 0; seg < 4; seg++)
        gll16(wtp + bOff + (long)seg * 64 * 2048 + ko,
              smem + 16384 + s * 16384 + seg * 4096 + d0);
      if (w < 2) gll16(pbp + pOff + ko, smem + 49152 + s * 2048 + d0);
    }
    const u16* At = (const u16*)(smem + cur * 8192);
    const u16* Bt = (const u16*)(smem + 16384 + cur * 16384);
    const u16* Pt = (const u16*)(smem + 49152 + cur * 2048);
    bf16x8 af[4], bq[8], bp;
#pragma unroll
    for (int tm = 0; tm < 4; tm++)
      af[tm] = *(const bf16x8*)(At + (mw + tm * 16 + lrow) * 32 + quad * 8);
#pragma unroll
    for (int tn = 0; tn < 8; tn++)
      bq[tn] = *(const bf16x8*)(Bt + (nw + tn * 16 + lrow) * 32 + quad * 8);
    bp = *(const bf16x8*)(Pt + (pc0 + lrow) * 32 + quad * 8);
#pragma unroll
    for (int tm = 0; tm < 4; tm++)
#pragma unroll
      for (int tn = 0; tn < 8; tn++)
        acc[tm][tn] = __builtin_amdgcn_mfma_f32_16x16x32_bf16(af[tm], bq[tn], acc[tm][tn], 0, 0, 0);
#pragma unroll
    for (int tm = 0; tm < 4; tm++)
      acc2[tm] = __builtin_amdgcn_mfma_f32_16x16x32_bf16(af[tm], bp, acc2[tm], 0, 0, 0);
    __syncthreads();
    cur ^= 1;
  }

  {
    const long rOff = ((long)n0 + w * 16 + sr) * 64 + sc;
#pragma unroll
    for (int seg = 0; seg < 4; seg++)
      gll16((const char*)RwT + rOff + (long)seg * 64 * 64,
            smem + 16384 + seg * 4096 + d0);
  }
  float* projF = (float*)smem;
#pragma unroll
  for (int tm = 0; tm < 4; tm++)
#pragma unroll
    for (int r = 0; r < 4; r++) {
      int row = mw + tm * 16 + quad * 4 + r;
      int col = pc0 + lrow;
      projF[row * 32 + (col ^ (row & 31))] = acc2[tm][r];
    }
  __syncthreads();
  if (tid < 128) {
    float pr[32];
#pragma unroll
    for (int j = 0; j < 32; j++) pr[j] = projF[tid * 32 + (j ^ (tid & 31))];
    float wo[32];
#pragma unroll
    for (int k = 0; k < 8; k++) { wo[k] = gl[k] * pr[8 + k]; wo[8 + k] = -gl[k] * pr[k]; }
#pragma unroll
    for (int kp = 0; kp < 8; kp++) {
      float sv = pr[16 + kp], tv = pr[24 + kp];
#pragma unroll
      for (int k = 0; k < 8; k++) {
        float gpb = gl[k] * pr[8 + k], gpa = gl[k] * pr[k];
        sv += gpb * Ml[k * 8 + kp]       - gpa * Ml[64 + k * 8 + kp];
        tv += gpb * Ml[128 + k * 8 + kp] - gpa * Ml[192 + k * 8 + kp];
      }
      wo[16 + kp] = gl[8 + kp] * sv;
      wo[24 + kp] = gl[16 + kp] * tv;
    }
    u16* wLds = (u16*)(smem + 32768);
#pragma unroll
    for (int j = 0; j < 32; j++) wLds[tid * 32 + j] = f2bf(wo[j]);
  }
  __syncthreads();
  {
    const u16* wL = (const u16*)(smem + 32768);
    const u16* Rt = (const u16*)(smem + 16384);
    bf16x8 af[4], bq[8];
#pragma unroll
    for (int tm = 0; tm < 4; tm++)
      af[tm] = *(const bf16x8*)(wL + (mw + tm * 16 + lrow) * 32 + quad * 8);
#pragma unroll
    for (int tn = 0; tn < 8; tn++)
      bq[tn] = *(const bf16x8*)(Rt + (nw + tn * 16 + lrow) * 32 + quad * 8);
#pragma unroll
    for (int tm = 0; tm < 4; tm++)
#pragma unroll
      for (int tn = 0; tn < 8; tn++)
        acc[tm][tn] = __builtin_amdgcn_mfma_f32_16x16x32_bf16(af[tm], bq[tn], acc[tm][tn], 0, 0, 0);
  }
#pragma unroll
  for (int tn = 0; tn < 8; tn++) {
    const int col = n0 + nw + tn * 16 + lrow;
    const float bias = bb[col];
#pragma unroll
    for (int tm = 0; tm < 4; tm++)
#pragma unroll
      for (int r = 0; r < 4; r++) {
        long row = m0 + mw + tm * 16 + quad * 4 + r;
        out[row * DD + col] = acc[tm][tn][r] + bias;
      }
  }
}

// ---------------------------------------------------------------------------
// mode-B fallback GEMM (register-staged path, fp32 x with convert)
// ---------------------------------------------------------------------------
template <bool XB>
__global__ __launch_bounds__(256) void k3_fused(
    const float* __restrict__ xf, const u16* __restrict__ xb,
    const u16* __restrict__ Wt, const u16* __restrict__ Pb,
    const float* __restrict__ gates, const float* __restrict__ Mbuf,
    const u16* __restrict__ RwT, const float* __restrict__ bb,
    float* __restrict__ out) {
  __shared__ __align__(16) u16 At[4096];
  __shared__ __align__(16) u16 Bt[4096];
  __shared__ __align__(16) u16 Pt[1024];
  __shared__ float projF[128 * 32];
  __shared__ __align__(16) u16 wLds[4096];
  __shared__ float Ml[256];
  __shared__ float gl[24];
  const int tid = threadIdx.x, lane = tid & 63, w = tid >> 6;
  const int quad = lane >> 4, lrow = lane & 15;
  const int bn = blockIdx.x & 7, bm = blockIdx.x >> 3;
  const long m0 = (long)bm * 128;
  const int n0 = bn * 128;
  const int batch = bm >> 5;
  Ml[tid] = Mbuf[tid];
  if (tid < 24) gl[tid] = gates[batch * 32 + tid];
  const int mw = (w & 1) * 64, nw = (w >> 1) * 64;
  const int p0 = (w * 2) * 1024 + lane * 16, p1 = p0 + 1024;
  f32x4 acc[4][4] = {};
  f32x4 acc2[2][2] = {};
  for (int kc = 0; kc < 32; kc++) {
    uint4 vb0 = *(const uint4*)((const char*)Wt + (long)(n0 + (p0 >> 6)) * 2048 + kc * 64 + (p0 & 63));
    uint4 vb1 = *(const uint4*)((const char*)Wt + (long)(n0 + (p1 >> 6)) * 2048 + kc * 64 + (p1 & 63));
    uint4 vp;
    if (tid < 128)
      vp = *(const uint4*)((const char*)Pb + (tid >> 2) * 2048 + kc * 64 + (tid & 3) * 16);
    if (XB) {
      uint4 va0 = *(const uint4*)((const char*)xb + (m0 + (p0 >> 6)) * 2048 + kc * 64 + (p0 & 63));
      uint4 va1 = *(const uint4*)((const char*)xb + (m0 + (p1 >> 6)) * 2048 + kc * 64 + (p1 & 63));
      *(uint4*)((char*)At + p0) = va0;
      *(uint4*)((char*)At + p1) = va1;
    } else {
      ushort4 oa[4];
#pragma unroll
      for (int i = 0; i < 4; i++) {
        int fi = i * 256 + tid, row = fi >> 3, c4 = (fi & 7) * 4;
        float4 v = *(const float4*)(xf + (m0 + row) * DD + kc * 32 + c4);
        oa[i].x = f2bf(v.x); oa[i].y = f2bf(v.y); oa[i].z = f2bf(v.z); oa[i].w = f2bf(v.w);
      }
#pragma unroll
      for (int i = 0; i < 4; i++) {
        int fi = i * 256 + tid, row = fi >> 3, c4 = (fi & 7) * 4;
        *(ushort4*)(At + row * 32 + c4) = oa[i];
      }
    }
    *(uint4*)((char*)Bt + p0) = vb0;
    *(uint4*)((char*)Bt + p1) = vb1;
    if (tid < 128) *(uint4*)((char*)Pt + (tid >> 2) * 64 + (tid & 3) * 16) = vp;
    __syncthreads();
    bf16x8 af[4], bq[4], af2[2], bp[2];
#pragma unroll
    for (int tm = 0; tm < 4; tm++)
      af[tm] = *(const bf16x8*)(At + (mw + tm * 16 + lrow) * 32 + quad * 8);
#pragma unroll
    for (int tn = 0; tn < 4; tn++)
      bq[tn] = *(const bf16x8*)(Bt + (nw + tn * 16 + lrow) * 32 + quad * 8);
#pragma unroll
    for (int t2 = 0; t2 < 2; t2++)
      af2[t2] = *(const bf16x8*)(At + (w * 32 + t2 * 16 + lrow) * 32 + quad * 8);
#pragma unroll
    for (int tn2 = 0; tn2 < 2; tn2++)
      bp[tn2] = *(const bf16x8*)(Pt + (tn2 * 16 + lrow) * 32 + quad * 8);
#pragma unroll
    for (int tm = 0; tm < 4; tm++)
#pragma unroll
      for (int tn = 0; tn < 4; tn++)
        acc[tm][tn] = __builtin_amdgcn_mfma_f32_16x16x32_bf16(af[tm], bq[tn], acc[tm][tn], 0, 0, 0);
#pragma unroll
    for (int t2 = 0; t2 < 2; t2++)
#pragma unroll
      for (int tn2 = 0; tn2 < 2; tn2++)
        acc2[t2][tn2] = __builtin_amdgcn_mfma_f32_16x16x32_bf16(af2[t2], bp[tn2], acc2[t2][tn2], 0, 0, 0);
    __syncthreads();
  }
#pragma unroll
  for (int t2 = 0; t2 < 2; t2++)
#pragma unroll
    for (int tn2 = 0; tn2 < 2; tn2++)
#pragma unroll
      for (int r = 0; r < 4; r++)
        projF[(w * 32 + t2 * 16 + quad * 4 + r) * 32 + tn2 * 16 + lrow] = acc2[t2][tn2][r];
  {
    uint4 vr0 = *(const uint4*)((const char*)RwT + (long)(n0 + (p0 >> 6)) * 64 + (p0 & 63));
    uint4 vr1 = *(const uint4*)((const char*)RwT + (long)(n0 + (p1 >> 6)) * 64 + (p1 & 63));
    *(uint4*)((char*)Bt + p0) = vr0;
    *(uint4*)((char*)Bt + p1) = vr1;
  }
  __syncthreads();
  if (tid < 128) {
    float pr[32];
#pragma unroll
    for (int j = 0; j < 32; j++) pr[j] = projF[tid * 32 + j];
    float wo[32];
#pragma unroll
    for (int k = 0; k < 8; k++) { wo[k] = gl[k] * pr[8 + k]; wo[8 + k] = -gl[k] * pr[k]; }
#pragma unroll
    for (int kp = 0; kp < 8; kp++) {
      float sv = pr[16 + kp], tv = pr[24 + kp];
#pragma unroll
      for (int k = 0; k < 8; k++) {
        float gpb = gl[k] * pr[8 + k], gpa = gl[k] * pr[k];
        sv += gpb * Ml[k * 8 + kp]       - gpa * Ml[64 + k * 8 + kp];
        tv += gpb * Ml[128 + k * 8 + kp] - gpa * Ml[192 + k * 8 + kp];
      }
      wo[16 + kp] = gl[8 + kp] * sv;
      wo[24 + kp] = gl[16 + kp] * tv;
    }
#pragma unroll
    for (int j = 0; j < 32; j++) wLds[tid * 32 + j] = f2bf(wo[j]);
  }
  __syncthreads();
  {
    bf16x8 af[4], bq[4];
#pragma unroll
    for (int tm = 0; tm < 4; tm++)
      af[tm] = *(const bf16x8*)(wLds + (mw + tm * 16 + lrow) * 32 + quad * 8);
#pragma unroll
    for (int tn = 0; tn < 4; tn++)
      bq[tn] = *(const bf16x8*)(Bt + (nw + tn * 16 + lrow) * 32 + quad * 8);
#pragma unroll
    for (int tm = 0; tm < 4; tm++)
#pragma unroll
      for (int tn = 0; tn < 4; tn++)
        acc[tm][tn] = __builtin_amdgcn_mfma_f32_16x16x32_bf16(af[tm], bq[tn], acc[tm][tn], 0, 0, 0);
  }
#pragma unroll
  for (int tn = 0; tn < 4; tn++) {
    const int col = n0 + nw + tn * 16 + lrow;
    const float bias = bb[col];
#pragma unroll
    for (int tm = 0; tm < 4; tm++)
#pragma unroll
      for (int r = 0; r < 4; r++) {
        long row = m0 + mw + tm * 16 + quad * 4 + r;
        out[row * DD + col] = acc[tm][tn][r] + bias;
      }
  }
}

// ---------------------------------------------------------------------------
extern "C" void kernel_launch(void* const* d_in, const int* in_sizes, int n_in,
                              void* d_out, int out_size, void* d_ws, size_t ws_size,
                              hipStream_t stream) {
  const float* x   = (const float*)d_in[0];
  const float* Wb  = (const float*)d_in[1];
  const float* bb  = (const float*)d_in[2];
  const float* lng = (const float*)d_in[3];
  const float* lnb = (const float*)d_in[4];
  const float* Wc1 = (const float*)d_in[5];
  const float* bc1 = (const float*)d_in[6];
  const float* Wc2 = (const float*)d_in[7];
  const float* bc2 = (const float*)d_in[8];
  const float* Wrg = (const float*)d_in[9];
  const float* brg = (const float*)d_in[10];
  const float* Wrc = (const float*)d_in[11];
  const float* brc = (const float*)d_in[12];
  const float* Wsg = (const float*)d_in[13];
  const float* bsg = (const float*)d_in[14];
  const float* Wlc = (const float*)d_in[15];
  const float* blc = (const float*)d_in[16];
  const float* Us  = (const float*)d_in[17];
  const float* Vs  = (const float*)d_in[18];
  const float* Ul  = (const float*)d_in[19];
  const float* Vl  = (const float*)d_in[20];
  const float* Ao  = (const float*)d_in[21];
  const float* Bo  = (const float*)d_in[22];

  char* ws = (char*)d_ws;
  float* pooled = (float*)(ws + 0);         //  4*1024 f32  [memset]
  float* AWBW   = (float*)(ws + 16384);     // 16*1024 f32  [memset]
  float* h1pre  = (float*)(ws + 81920);     //  4*128 f32   [memset] -> 83968
  float* gates  = (float*)(ws + 83968);     //  4*32  f32   -> 84480
  float* Mbuf   = (float*)(ws + 84480);     //  256   f32   -> 85504
  u32*   cntH   = (u32*)  (ws + 85504);     //  counter [memset] -> 85568
  u16*   RwT    = (u16*)  (ws + 85568);     // 1024*32 bf16 -> 151104
  u16*   Pb     = (u16*)  (ws + 151104);    // 32*1024 bf16 -> 216640
  u16*   Wt     = (u16*)  (ws + 216640);    // 1024*1024 bf16 (2 MB) -> 2313792
  u16*   xb     = (u16*)  (ws + 2313792);   // 16384*1024 bf16 (32 MB), mode A
  float* out    = (float*)d_out;

  const bool modeA = ws_size >= (size_t)2313792 + 33554432;

  (void)hipMemsetAsync(d_ws, 0, 85568, stream);   // pooled+AWBW+h1pre+cnt
  kA_heavy<<<328, 256, 0, stream>>>(Wb, Ao, Bo, Us, Ul, AWBW, Mbuf, Pb, Wt);
  if (modeA)
    kB_stream<true><<<1024, 256, 0, stream>>>(x, xb, pooled);
  else
    kB_stream<false><<<1024, 256, 0, stream>>>(x, xb, pooled);
  k2ab<<<40, 256, 0, stream>>>(pooled, lng, lnb, Wc1, h1pre,
                               AWBW, Vs, Vl, bc1, Wc2, bc2,
                               Wrg, brg, Wrc, brc, Wsg, bsg, Wlc, blc,
                               gates, RwT, cntH);
  if (modeA)
    k3b_fused<<<512, 256, 0, stream>>>(xb, Wt, Pb, gates, Mbuf, RwT, bb, out);
  else
    k3_fused<false><<<1024, 256, 0, stream>>>(x, xb, Wt, Pb, gates, Mbuf, RwT, bb, out);
}

// Round 10
// 264.152 us; speedup vs baseline: 1.0982x; 1.0982x over previous
//
#include <hip/hip_runtime.h>

typedef unsigned short u16;
typedef unsigned int   u32;
typedef __bf16 bf16x8 __attribute__((ext_vector_type(8)));
typedef float  f32x4  __attribute__((ext_vector_type(4)));

#define DD 1024

__device__ __forceinline__ u16 f2bf(float f) {
  u32 u = __float_as_uint(f);
  u32 r = (u + 0x7FFFu + ((u >> 16) & 1u)) >> 16;
  return (u16)r;
}

// async global->LDS, 16B per lane. Dest must be wave-uniform-base + lane*16.
typedef const __attribute__((address_space(1))) void* gp1;
typedef __attribute__((address_space(3))) void* lp3;
__device__ __forceinline__ void gll16(const void* g, void* l) {
  __builtin_amdgcn_global_load_lds((gp1)g, (lp3)l, 16, 0, 0);
}

// ---------------------------------------------------------------------------
// k01m: merged pre-kernel (r8 structure, best total) + gll16 streamer fix.
// blocks 0..63   : AWBW partials; signal cntW.
// blocks 64..67  : Mbuf Gram.
// blocks 68..71  : Pb pack.
// blocks 72..327 : Wt transpose.
// blocks 328..839: STREAMER, rebuilt: double-buffered global_load_lds staging
//   (2 rows = 8KB/chunk, 16 chunks). Rationale: r8's VGPR-held loads gave
//   1KB in flight/CU (VGPR=40 -> 2 loads/wave) = the measured ~1 TB/s.
//   gll16 gives 1KB/call with zero registers -> 64KB/CU in flight.
//   Phase order stage-next / process-cur / barrier (k3b-proven overlap).
//   Signal cntS.
// blocks 840..871: LN + z@Wc1 (spin cntS==512) -> h1pre; signal cntH.
// blocks 872..875: gates (spin cntH==32); head weights STAGED IN LDS
//   (r9 read them per-element from global in a 128-iter serial loop).
// blocks 876..879: pack RwT (spin cntW==64).
// All 880 blocks co-resident (16.4KB LDS, 8 blocks/CU thread-cap binder).
// ---------------------------------------------------------------------------
template <bool XB>
__global__ __launch_bounds__(256) void k01m(
    const float* __restrict__ x, u16* __restrict__ xb, float* __restrict__ pooled,
    const float* __restrict__ W,
    const float* __restrict__ Ao, const float* __restrict__ Bo,
    const float* __restrict__ Us, const float* __restrict__ Ul,
    float* __restrict__ AWBW, float* __restrict__ Mbuf,
    u16* __restrict__ Pb, u16* __restrict__ Wt,
    const float* __restrict__ lng, const float* __restrict__ lnb,
    const float* __restrict__ Wc1, float* __restrict__ h1pre,
    const float* Vs, const float* Vl,
    const float* bc1, const float* Wc2, const float* bc2,
    const float* Wrg, const float* brg, const float* Wrc, const float* brc,
    const float* Wsg, const float* bsg, const float* Wlc, const float* blc,
    float* __restrict__ gates, u16* __restrict__ RwT,
    u32* __restrict__ cntS, u32* __restrict__ cntH, u32* __restrict__ cntW) {
  __shared__ __align__(16) char shb[16384];   // union across branches
  const int tid = threadIdx.x;
  const int bid = blockIdx.x;

  if (bid >= 328 && bid < 840) {
    // ---- streamer: gll16-staged convert + pooled sums ----
    const int i = bid - 328;                   // dispatch XCD = i%8 (328%8==0)
    const int xcd = i & 7, local = i >> 3;     // local 0..63
    const int rb = xcd * 64 + local;           // row-block 0..511 (32 rows ea)
    const int b = rb >> 7;                     // batch (128 rb per batch)
    const long r0 = (long)rb * 32;
    const char* xfb = (const char*)x;
    const int trow = tid >> 7;                 // row-within-chunk (process)
    const int tcol = (tid & 127) * 8;          // float col base (process)
    float p[8];
#pragma unroll
    for (int j = 0; j < 8; j++) p[j] = 0.f;
    // prologue: stage chunk 0 -> buf0
    gll16(xfb + r0 * 4096 + tid * 16,        shb + tid * 16);
    gll16(xfb + (r0 + 1) * 4096 + tid * 16,  shb + 4096 + tid * 16);
    __syncthreads();
    int cur = 0;
    for (int c = 0; c < 16; c++) {
      if (c < 15) {                            // stage chunk c+1 -> buf cur^1
        const long rowb = (r0 + (long)(c + 1) * 2) * 4096;
        const int s = cur ^ 1;
        gll16(xfb + rowb + tid * 16,        shb + s * 8192 + tid * 16);
        gll16(xfb + rowb + 4096 + tid * 16, shb + s * 8192 + 4096 + tid * 16);
      }
      // process buf cur (ready: previous barrier drained its gll16s)
      const char* bp = shb + cur * 8192 + trow * 4096 + (tid & 127) * 32;
      f32x4 u = *(const f32x4*)bp;
      f32x4 v = *(const f32x4*)(bp + 16);
      if (XB) {
        uint4 o;
        o.x = (u32)f2bf(u[0]) | ((u32)f2bf(u[1]) << 16);
        o.y = (u32)f2bf(u[2]) | ((u32)f2bf(u[3]) << 16);
        o.z = (u32)f2bf(v[0]) | ((u32)f2bf(v[1]) << 16);
        o.w = (u32)f2bf(v[2]) | ((u32)f2bf(v[3]) << 16);
        *(uint4*)((char*)xb + (r0 + (long)c * 2 + trow) * 2048 + (tid & 127) * 16) = o;
      }
      p[0] += u[0]; p[1] += u[1]; p[2] += u[2]; p[3] += u[3];
      p[4] += v[0]; p[5] += v[1]; p[6] += v[2]; p[7] += v[3];
      __syncthreads();   // drains prefetch gll16s -> publishes buf cur^1
      cur ^= 1;
    }
    // pair-reduce (t, t+128 share cols) then 1024 atomics/block
    float* rsh = (float*)shb;
#pragma unroll
    for (int j = 0; j < 8; j++) rsh[tid * 8 + j] = p[j];
    __syncthreads();
    if (tid < 128) {
#pragma unroll
      for (int j = 0; j < 8; j++) {
        float sres = rsh[tid * 8 + j] + rsh[(tid + 128) * 8 + j];
        atomicAdd(&pooled[b * DD + tcol + j], sres);
      }
    }
    __syncthreads();                           // drain stores + atomics
    if (tid == 0) atomicAdd(cntS, 1u);
    return;
  }
  if (bid < 64) {
    // ---- AWBW: 64 blocks, 64-iteration serial chain ----
    float (*red2)[128][16] = (float (*)[128][16])shb;   // 16384 B
    const int m = bid;
    const int n = (m & 7) * 128 + (tid & 127), q = m >> 3, ih = tid >> 7;
    float acc[16];
#pragma unroll
    for (int k = 0; k < 16; k++) acc[k] = 0.f;
    const int ib = q * 128 + ih * 64;
    for (int i = ib; i < ib + 64; i++) {
      float wv = W[(long)i * DD + n];
#pragma unroll
      for (int k = 0; k < 8; k++) {
        acc[k]     += Ao[k * DD + i] * wv;
        acc[k + 8] += Bo[k * DD + i] * wv;
      }
    }
#pragma unroll
    for (int k = 0; k < 16; k++) red2[ih][tid & 127][k] = acc[k];
    __syncthreads();
    if (ih == 0)
#pragma unroll
      for (int k = 0; k < 16; k++)
        atomicAdd(&AWBW[k * DD + n], red2[0][tid][k] + red2[1][tid][k]);
    __syncthreads();                           // drain atomics
    if (tid == 0) atomicAdd(cntW, 1u);
  } else if (bid < 68) {
    float (*red)[4] = (float (*)[4])shb;                // 1024 B
    const int m = bid - 64;
    const float* L  = (m == 0 || m == 2) ? Ao : Bo;
    const float* Rr = (m < 2) ? Us : Ul;
    const int o = tid >> 2, ch = tid & 3;
    const int k = o >> 3, kp = o & 7;
    float a = 0.f;
    for (int i = ch * 256; i < ch * 256 + 256; i++)
      a += L[(long)k * DD + i] * Rr[(long)kp * DD + i];
    red[o][ch] = a;
    __syncthreads();
    if (tid < 64) Mbuf[m * 64 + tid] = red[tid][0] + red[tid][1] + red[tid][2] + red[tid][3];
  } else if (bid < 72) {
    const int m = bid - 68;
    const float* src = m == 0 ? Ao : m == 1 ? Bo : m == 2 ? Us : Ul;
#pragma unroll
    for (int j = 0; j < 8; j++)
      for (int q = 0; q < 4; q++) {
        int i = q * 256 + tid;
        Pb[(m * 8 + j) * DD + i] = f2bf(src[j * DD + i]);
      }
  } else if (bid < 328) {
    u16 (*T)[66] = (u16 (*)[66])shb;                    // 8448 B
    const int t = bid - 72, tr = t >> 4, tc = t & 15;
#pragma unroll
    for (int q2 = 0; q2 < 16; q2++) {
      int idx = q2 * 256 + tid, r = idx >> 6, c = idx & 63;
      T[r][c] = f2bf(W[(long)(tr * 64 + r) * DD + tc * 64 + c]);
    }
    __syncthreads();
#pragma unroll
    for (int q2 = 0; q2 < 16; q2++) {
      int idx = q2 * 256 + tid, c = idx >> 6, r = idx & 63;
      Wt[(long)(tc * 64 + c) * DD + tr * 64 + r] = T[r][c];
    }
  } else if (bid < 872) {
    // ---- LN + z@Wc1 partial (spin on streamers) ----
    float* zs  = (float*)shb;                  // 1024 f32
    float* red = (float*)(shb + 4096);         // 256 f32
    const int lb = bid - 840;
    const int b = lb >> 3, ch = lb & 7;
    if (tid == 0) {
      while (atomicAdd(cntS, 0u) < 512u) __builtin_amdgcn_s_sleep(8);
    }
    __syncthreads();
    float4 v;
    v.x = atomicAdd(&pooled[b * DD + tid * 4 + 0], 0.f);   // coherent reads
    v.y = atomicAdd(&pooled[b * DD + tid * 4 + 1], 0.f);
    v.z = atomicAdd(&pooled[b * DD + tid * 4 + 2], 0.f);
    v.w = atomicAdd(&pooled[b * DD + tid * 4 + 3], 0.f);
    v.x *= (1.f / 4096.f); v.y *= (1.f / 4096.f); v.z *= (1.f / 4096.f); v.w *= (1.f / 4096.f);
    float s = v.x + v.y + v.z + v.w;
    float sq = v.x * v.x + v.y * v.y + v.z * v.z + v.w * v.w;
    red[tid] = s; __syncthreads();
    for (int st = 128; st > 0; st >>= 1) { if (tid < st) red[tid] += red[tid + st]; __syncthreads(); }
    float mu = red[0] * (1.f / 1024.f);
    __syncthreads();
    red[tid] = sq; __syncthreads();
    for (int st = 128; st > 0; st >>= 1) { if (tid < st) red[tid] += red[tid + st]; __syncthreads(); }
    float var = red[0] * (1.f / 1024.f) - mu * mu;
    float rs = rsqrtf(var + 1e-5f);
    __syncthreads();
    {
      float4 g = *(const float4*)(lng + tid * 4);
      float4 be = *(const float4*)(lnb + tid * 4);
      zs[tid * 4 + 0] = (v.x - mu) * rs * g.x + be.x;
      zs[tid * 4 + 1] = (v.y - mu) * rs * g.y + be.y;
      zs[tid * 4 + 2] = (v.z - mu) * rs * g.z + be.z;
      zs[tid * 4 + 3] = (v.w - mu) * rs * g.w + be.w;
    }
    __syncthreads();
    const int j = tid & 127, half = tid >> 7;
    float a = 0.f;
#pragma unroll 8
    for (int dd = 0; dd < 64; dd++) {
      int ldi = half * 64 + dd;
      a += zs[ch * 128 + ldi] * Wc1[(long)ch * 16384 + ldi * 128 + j];
    }
    red[tid] = a;
    __syncthreads();
    if (tid < 128) atomicAdd(&h1pre[b * 128 + tid], red[tid] + red[tid + 128]);
    __syncthreads();
    if (tid == 0) atomicAdd(cntH, 1u);
  } else if (bid < 876) {
    // ---- gates for batch b (spin on LN); head weights staged in LDS ----
    float* h1s = (float*)shb;                  // 128 f
    float* hb  = (float*)(shb + 512);          // 128 f
    float* red = (float*)(shb + 1024);         // 256 f
    float* hw  = (float*)(shb + 2048);         // 3200 f -> ends 14848
    const int b = bid - 872;
    for (int idx = tid; idx < 3200; idx += 256) {   // stage BEFORE spin
      float vv;
      if (idx < 128)       vv = Wrg[idx];
      else if (idx < 1152) vv = Wrc[idx - 128];
      else if (idx < 2176) vv = Wsg[idx - 1152];
      else                 vv = Wlc[idx - 2176];
      hw[idx] = vv;
    }
    if (tid == 0) {
      while (atomicAdd(cntH, 0u) < 32u) __builtin_amdgcn_s_sleep(8);
    }
    __syncthreads();
    if (tid < 128) {
      float hv = atomicAdd(&h1pre[b * 128 + tid], 0.f) + bc1[tid];
      float th = tanhf(0.7978845608028654f * (hv + 0.044715f * hv * hv * hv));
      h1s[tid] = 0.5f * hv * (1.f + th);
    }
    __syncthreads();
    const int i = tid & 127, half = tid >> 7;
    float a = 0.f;
#pragma unroll 8
    for (int k = 0; k < 64; k++) {
      int kk = half * 64 + k;
      a += h1s[kk] * Wc2[kk * 128 + i];
    }
    red[tid] = a;
    __syncthreads();
    if (tid < 128) hb[tid] = red[tid] + red[tid + 128] + bc2[tid];
    __syncthreads();
    if (tid < 25) {
      float acc;
      if (tid == 0) {
        acc = brg[0];
        for (int k = 0; k < 128; k++) acc += hb[k] * hw[k];
        red[0] = 1.f / (1.f + expf(-acc));
      } else if (tid < 9) {
        int ci = tid - 1; acc = brc[ci];
        for (int k = 0; k < 128; k++) acc += hb[k] * hw[128 + k * 8 + ci];
        red[tid] = tanhf(acc);
      } else if (tid < 17) {
        int ci = tid - 9; acc = bsg[ci];
        for (int k = 0; k < 128; k++) acc += hb[k] * hw[1152 + k * 8 + ci];
        red[tid] = tanhf(acc);
      } else {
        int ci = tid - 17; acc = blc[ci];
        for (int k = 0; k < 128; k++) acc += hb[k] * hw[2176 + k * 8 + ci];
        red[tid] = tanhf(acc);
      }
    }
    __syncthreads();
    if (tid < 24) {
      float g = red[0];
      gates[b * 32 + tid] = (tid < 8) ? g * red[1 + tid] : red[1 + tid];
    }
  } else {
    // ---- pack RwT (spin on AWBW) ----
    if (tid == 0) {
      while (atomicAdd(cntW, 0u) < 64u) __builtin_amdgcn_s_sleep(8);
    }
    __syncthreads();
    const int n = (int)(bid - 876) * 256 + tid;
#pragma unroll
    for (int j = 0; j < 8; j++) {
      RwT[n * 32 + j]      = f2bf(atomicAdd(&AWBW[j * DD + n], 0.f));
      RwT[n * 32 + 8 + j]  = f2bf(atomicAdd(&AWBW[(8 + j) * DD + n], 0.f));
      RwT[n * 32 + 16 + j] = f2bf(Vs[(long)j * DD + n]);
      RwT[n * 32 + 24 + j] = f2bf(Vl[(long)j * DD + n]);
    }
  }
}

// ---------------------------------------------------------------------------
// k3b (mode A): fused GEMM, 128x256 tile, 512 blocks @ 2 blocks/CU.
// Double-buffered gll16, one barrier/chunk, XCD-bijective swizzle.
// (unchanged — steady-state ~82us)
// ---------------------------------------------------------------------------
__global__ __launch_bounds__(256, 2) void k3b_fused(
    const u16* __restrict__ xb, const u16* __restrict__ Wt,
    const u16* __restrict__ Pb, const float* __restrict__ gates,
    const float* __restrict__ Mbuf, const u16* __restrict__ RwT,
    const float* __restrict__ bb, float* __restrict__ out) {
  __shared__ __align__(16) char smem[54400];
  const int tid = threadIdx.x, lane = tid & 63, w = tid >> 6;
  const int quad = lane >> 4, lrow = lane & 15;
  const int g = blockIdx.x;
  const int xcd = g & 7, local = g >> 3;
  const int bm = xcd * 16 + (local >> 2);
  const int bn2 = local & 3;
  const long m0 = (long)bm * 128;
  const int n0 = bn2 * 256;
  const int batch = bm >> 5;
  float* Ml = (float*)(smem + 53248);
  float* gl = (float*)(smem + 54272);
  Ml[tid] = Mbuf[tid];
  if (tid < 24) gl[tid] = gates[batch * 32 + tid];
  const int mw = (w & 1) * 64, nw = (w >> 1) * 128;
  const int pc0 = (w >> 1) * 16;
  const int sr = lane >> 2, sc = (lane & 3) * 16;
  const char* xbp = (const char*)xb;
  const char* wtp = (const char*)Wt;
  const char* pbp = (const char*)Pb;
  const long aOff0 = (m0 + (long)w * 16 + sr) * 2048 + sc;
  const long aOff1 = aOff0 + 64 * 2048;
  const long bOff  = ((long)n0 + w * 16 + sr) * 2048 + sc;
  const long pOff  = ((long)w * 16 + sr) * 2048 + sc;
  const int d0 = w * 1024 + lane * 16;

  f32x4 acc[4][8] = {};
  f32x4 acc2[4] = {};

  gll16(xbp + aOff0, smem + d0);
  gll16(xbp + aOff1, smem + d0 + 4096);
#pragma unroll
  for (int seg = 0; seg < 4; seg++)
    gll16(wtp + bOff + (long)seg * 64 * 2048, smem + 16384 + seg * 4096 + d0);
  if (w < 2) gll16(pbp + pOff, smem + 49152 + d0);
  __syncthreads();

  int cur = 0;
  for (int kc = 0; kc < 32; kc++) {
    if (kc < 31) {
      const long ko = (long)(kc + 1) * 64;
      const int s = cur ^ 1;
      gll16(xbp + aOff0 + ko, smem + s * 8192 + d0);
      gll16(xbp + aOff1 + ko, smem + s * 8192 + d0 + 4096);
#pragma unroll
      for (int seg = 0; seg < 4; seg++)
        gll16(wtp + bOff + (long)seg * 64 * 2048 + ko,
              smem + 16384 + s * 16384 + seg * 4096 + d0);
      if (w < 2) gll16(pbp + pOff + ko, smem + 49152 + s * 2048 + d0);
    }
    const u16* At = (const u16*)(smem + cur * 8192);
    const u16* Bt = (const u16*)(smem + 16384 + cur * 16384);
    const u16* Pt = (const u16*)(smem + 49152 + cur * 2048);
    bf16x8 af[4], bq[8], bp;
#pragma unroll
    for (int tm = 0; tm < 4; tm++)
      af[tm] = *(const bf16x8*)(At + (mw + tm * 16 + lrow) * 32 + quad * 8);
#pragma unroll
    for (int tn = 0; tn < 8; tn++)
      bq[tn] = *(const bf16x8*)(Bt + (nw + tn * 16 + lrow) * 32 + quad * 8);
    bp = *(const bf16x8*)(Pt + (pc0 + lrow) * 32 + quad * 8);
#pragma unroll
    for (int tm = 0; tm < 4; tm++)
#pragma unroll
      for (int tn = 0; tn < 8; tn++)
        acc[tm][tn] = __builtin_amdgcn_mfma_f32_16x16x32_bf16(af[tm], bq[tn], acc[tm][tn], 0, 0, 0);
#pragma unroll
    for (int tm = 0; tm < 4; tm++)
      acc2[tm] = __builtin_amdgcn_mfma_f32_16x16x32_bf16(af[tm], bp, acc2[tm], 0, 0, 0);
    __syncthreads();
    cur ^= 1;
  }

  {
    const long rOff = ((long)n0 + w * 16 + sr) * 64 + sc;
#pragma unroll
    for (int seg = 0; seg < 4; seg++)
      gll16((const char*)RwT + rOff + (long)seg * 64 * 64,
            smem + 16384 + seg * 4096 + d0);
  }
  float* projF = (float*)smem;
#pragma unroll
  for (int tm = 0; tm < 4; tm++)
#pragma unroll
    for (int r = 0; r < 4; r++) {
      int row = mw + tm * 16 + quad * 4 + r;
      int col = pc0 + lrow;
      projF[row * 32 + (col ^ (row & 31))] = acc2[tm][r];
    }
  __syncthreads();
  if (tid < 128) {
    float pr[32];
#pragma unroll
    for (int j = 0; j < 32; j++) pr[j] = projF[tid * 32 + (j ^ (tid & 31))];
    float wo[32];
#pragma unroll
    for (int k = 0; k < 8; k++) { wo[k] = gl[k] * pr[8 + k]; wo[8 + k] = -gl[k] * pr[k]; }
#pragma unroll
    for (int kp = 0; kp < 8; kp++) {
      float sv = pr[16 + kp], tv = pr[24 + kp];
#pragma unroll
      for (int k = 0; k < 8; k++) {
        float gpb = gl[k] * pr[8 + k], gpa = gl[k] * pr[k];
        sv += gpb * Ml[k * 8 + kp]       - gpa * Ml[64 + k * 8 + kp];
        tv += gpb * Ml[128 + k * 8 + kp] - gpa * Ml[192 + k * 8 + kp];
      }
      wo[16 + kp] = gl[8 + kp] * sv;
      wo[24 + kp] = gl[16 + kp] * tv;
    }
    u16* wLds = (u16*)(smem + 32768);
#pragma unroll
    for (int j = 0; j < 32; j++) wLds[tid * 32 + j] = f2bf(wo[j]);
  }
  __syncthreads();
  {
    const u16* wL = (const u16*)(smem + 32768);
    const u16* Rt = (const u16*)(smem + 16384);
    bf16x8 af[4], bq[8];
#pragma unroll
    for (int tm = 0; tm < 4; tm++)
      af[tm] = *(const bf16x8*)(wL + (mw + tm * 16 + lrow) * 32 + quad * 8);
#pragma unroll
    for (int tn = 0; tn < 8; tn++)
      bq[tn] = *(const bf16x8*)(Rt + (nw + tn * 16 + lrow) * 32 + quad * 8);
#pragma unroll
    for (int tm = 0; tm < 4; tm++)
#pragma unroll
      for (int tn = 0; tn < 8; tn++)
        acc[tm][tn] = __builtin_amdgcn_mfma_f32_16x16x32_bf16(af[tm], bq[tn], acc[tm][tn], 0, 0, 0);
  }
#pragma unroll
  for (int tn = 0; tn < 8; tn++) {
    const int col = n0 + nw + tn * 16 + lrow;
    const float bias = bb[col];
#pragma unroll
    for (int tm = 0; tm < 4; tm++)
#pragma unroll
      for (int r = 0; r < 4; r++) {
        long row = m0 + mw + tm * 16 + quad * 4 + r;
        out[row * DD + col] = acc[tm][tn][r] + bias;
      }
  }
}

// ---------------------------------------------------------------------------
// mode-B fallback GEMM (register-staged path, fp32 x with convert)
// ---------------------------------------------------------------------------
template <bool XB>
__global__ __launch_bounds__(256) void k3_fused(
    const float* __restrict__ xf, const u16* __restrict__ xb,
    const u16* __restrict__ Wt, const u16* __restrict__ Pb,
    const float* __restrict__ gates, const float* __restrict__ Mbuf,
    const u16* __restrict__ RwT, const float* __restrict__ bb,
    float* __restrict__ out) {
  __shared__ __align__(16) u16 At[4096];
  __shared__ __align__(16) u16 Bt[4096];
  __shared__ __align__(16) u16 Pt[1024];
  __shared__ float projF[128 * 32];
  __shared__ __align__(16) u16 wLds[4096];
  __shared__ float Ml[256];
  __shared__ float gl[24];
  const int tid = threadIdx.x, lane = tid & 63, w = tid >> 6;
  const int quad = lane >> 4, lrow = lane & 15;
  const int bn = blockIdx.x & 7, bm = blockIdx.x >> 3;
  const long m0 = (long)bm * 128;
  const int n0 = bn * 128;
  const int batch = bm >> 5;
  Ml[tid] = Mbuf[tid];
  if (tid < 24) gl[tid] = gates[batch * 32 + tid];
  const int mw = (w & 1) * 64, nw = (w >> 1) * 64;
  const int p0 = (w * 2) * 1024 + lane * 16, p1 = p0 + 1024;
  f32x4 acc[4][4] = {};
  f32x4 acc2[2][2] = {};
  for (int kc = 0; kc < 32; kc++) {
    uint4 vb0 = *(const uint4*)((const char*)Wt + (long)(n0 + (p0 >> 6)) * 2048 + kc * 64 + (p0 & 63));
    uint4 vb1 = *(const uint4*)((const char*)Wt + (long)(n0 + (p1 >> 6)) * 2048 + kc * 64 + (p1 & 63));
    uint4 vp;
    if (tid < 128)
      vp = *(const uint4*)((const char*)Pb + (tid >> 2) * 2048 + kc * 64 + (tid & 3) * 16);
    if (XB) {
      uint4 va0 = *(const uint4*)((const char*)xb + (m0 + (p0 >> 6)) * 2048 + kc * 64 + (p0 & 63));
      uint4 va1 = *(const uint4*)((const char*)xb + (m0 + (p1 >> 6)) * 2048 + kc * 64 + (p1 & 63));
      *(uint4*)((char*)At + p0) = va0;
      *(uint4*)((char*)At + p1) = va1;
    } else {
      ushort4 oa[4];
#pragma unroll
      for (int i = 0; i < 4; i++) {
        int fi = i * 256 + tid, row = fi >> 3, c4 = (fi & 7) * 4;
        float4 v = *(const float4*)(xf + (m0 + row) * DD + kc * 32 + c4);
        oa[i].x = f2bf(v.x); oa[i].y = f2bf(v.y); oa[i].z = f2bf(v.z); oa[i].w = f2bf(v.w);
      }
#pragma unroll
      for (int i = 0; i < 4; i++) {
        int fi = i * 256 + tid, row = fi >> 3, c4 = (fi & 7) * 4;
        *(ushort4*)(At + row * 32 + c4) = oa[i];
      }
    }
    *(uint4*)((char*)Bt + p0) = vb0;
    *(uint4*)((char*)Bt + p1) = vb1;
    if (tid < 128) *(uint4*)((char*)Pt + (tid >> 2) * 64 + (tid & 3) * 16) = vp;
    __syncthreads();
    bf16x8 af[4], bq[4], af2[2], bp[2];
#pragma unroll
    for (int tm = 0; tm < 4; tm++)
      af[tm] = *(const bf16x8*)(At + (mw + tm * 16 + lrow) * 32 + quad * 8);
#pragma unroll
    for (int tn = 0; tn < 4; tn++)
      bq[tn] = *(const bf16x8*)(Bt + (nw + tn * 16 + lrow) * 32 + quad * 8);
#pragma unroll
    for (int t2 = 0; t2 < 2; t2++)
      af2[t2] = *(const bf16x8*)(At + (w * 32 + t2 * 16 + lrow) * 32 + quad * 8);
#pragma unroll
    for (int tn2 = 0; tn2 < 2; tn2++)
      bp[tn2] = *(const bf16x8*)(Pt + (tn2 * 16 + lrow) * 32 + quad * 8);
#pragma unroll
    for (int tm = 0; tm < 4; tm++)
#pragma unroll
      for (int tn = 0; tn < 4; tn++)
        acc[tm][tn] = __builtin_amdgcn_mfma_f32_16x16x32_bf16(af[tm], bq[tn], acc[tm][tn], 0, 0, 0);
#pragma unroll
    for (int t2 = 0; t2 < 2; t2++)
#pragma unroll
      for (int tn2 = 0; tn2 < 2; tn2++)
        acc2[t2][tn2] = __builtin_amdgcn_mfma_f32_16x16x32_bf16(af2[t2], bp[tn2], acc2[t2][tn2], 0, 0, 0);
    __syncthreads();
  }
#pragma unroll
  for (int t2 = 0; t2 < 2; t2++)
#pragma unroll
    for (int tn2 = 0; tn2 < 2; tn2++)
#pragma unroll
      for (int r = 0; r < 4; r++)
        projF[(w * 32 + t2 * 16 + quad * 4 + r) * 32 + tn2 * 16 + lrow] = acc2[t2][tn2][r];
  {
    uint4 vr0 = *(const uint4*)((const char*)RwT + (long)(n0 + (p0 >> 6)) * 64 + (p0 & 63));
    uint4 vr1 = *(const uint4*)((const char*)RwT + (long)(n0 + (p1 >> 6)) * 64 + (p1 & 63));
    *(uint4*)((char*)Bt + p0) = vr0;
    *(uint4*)((char*)Bt + p1) = vr1;
  }
  __syncthreads();
  if (tid < 128) {
    float pr[32];
#pragma unroll
    for (int j = 0; j < 32; j++) pr[j] = projF[tid * 32 + j];
    float wo[32];
#pragma unroll
    for (int k = 0; k < 8; k++) { wo[k] = gl[k] * pr[8 + k]; wo[8 + k] = -gl[k] * pr[k]; }
#pragma unroll
    for (int kp = 0; kp < 8; kp++) {
      float sv = pr[16 + kp], tv = pr[24 + kp];
#pragma unroll
      for (int k = 0; k < 8; k++) {
        float gpb = gl[k] * pr[8 + k], gpa = gl[k] * pr[k];
        sv += gpb * Ml[k * 8 + kp]       - gpa * Ml[64 + k * 8 + kp];
        tv += gpb * Ml[128 + k * 8 + kp] - gpa * Ml[192 + k * 8 + kp];
      }
      wo[16 + kp] = gl[8 + kp] * sv;
      wo[24 + kp] = gl[16 + kp] * tv;
    }
#pragma unroll
    for (int j = 0; j < 32; j++) wLds[tid * 32 + j] = f2bf(wo[j]);
  }
  __syncthreads();
  {
    bf16x8 af[4], bq[4];
#pragma unroll
    for (int tm = 0; tm < 4; tm++)
      af[tm] = *(const bf16x8*)(wLds + (mw + tm * 16 + lrow) * 32 + quad * 8);
#pragma unroll
    for (int tn = 0; tn < 4; tn++)
      bq[tn] = *(const bf16x8*)(Bt + (nw + tn * 16 + lrow) * 32 + quad * 8);
#pragma unroll
    for (int tm = 0; tm < 4; tm++)
#pragma unroll
      for (int tn = 0; tn < 4; tn++)
        acc[tm][tn] = __builtin_amdgcn_mfma_f32_16x16x32_bf16(af[tm], bq[tn], acc[tm][tn], 0, 0, 0);
  }
#pragma unroll
  for (int tn = 0; tn < 4; tn++) {
    const int col = n0 + nw + tn * 16 + lrow;
    const float bias = bb[col];
#pragma unroll
    for (int tm = 0; tm < 4; tm++)
#pragma unroll
      for (int r = 0; r < 4; r++) {
        long row = m0 + mw + tm * 16 + quad * 4 + r;
        out[row * DD + col] = acc[tm][tn][r] + bias;
      }
  }
}

// ---------------------------------------------------------------------------
extern "C" void kernel_launch(void* const* d_in, const int* in_sizes, int n_in,
                              void* d_out, int out_size, void* d_ws, size_t ws_size,
                              hipStream_t stream) {
  const float* x   = (const float*)d_in[0];
  const float* Wb  = (const float*)d_in[1];
  const float* bb  = (const float*)d_in[2];
  const float* lng = (const float*)d_in[3];
  const float* lnb = (const float*)d_in[4];
  const float* Wc1 = (const float*)d_in[5];
  const float* bc1 = (const float*)d_in[6];
  const float* Wc2 = (const float*)d_in[7];
  const float* bc2 = (const float*)d_in[8];
  const float* Wrg = (const float*)d_in[9];
  const float* brg = (const float*)d_in[10];
  const float* Wrc = (const float*)d_in[11];
  const float* brc = (const float*)d_in[12];
  const float* Wsg = (const float*)d_in[13];
  const float* bsg = (const float*)d_in[14];
  const float* Wlc = (const float*)d_in[15];
  const float* blc = (const float*)d_in[16];
  const float* Us  = (const float*)d_in[17];
  const float* Vs  = (const float*)d_in[18];
  const float* Ul  = (const float*)d_in[19];
  const float* Vl  = (const float*)d_in[20];
  const float* Ao  = (const float*)d_in[21];
  const float* Bo  = (const float*)d_in[22];

  char* ws = (char*)d_ws;
  float* pooled = (float*)(ws + 0);         //  4*1024 f32  [memset]
  float* AWBW   = (float*)(ws + 16384);     // 16*1024 f32  [memset]
  float* h1pre  = (float*)(ws + 81920);     //  4*128 f32   [memset] -> 83968
  float* gates  = (float*)(ws + 83968);     //  4*32  f32   -> 84480
  float* Mbuf   = (float*)(ws + 84480);     //  256   f32   -> 85504
  u32*   cntH   = (u32*)  (ws + 85504);     //  counters [memset]
  u32*   cntS   = (u32*)  (ws + 85508);
  u32*   cntW   = (u32*)  (ws + 85512);     //  -> 85568
  u16*   RwT    = (u16*)  (ws + 85568);     // 1024*32 bf16 -> 151104
  u16*   Pb     = (u16*)  (ws + 151104);    // 32*1024 bf16 -> 216640
  u16*   Wt     = (u16*)  (ws + 216640);    // 1024*1024 bf16 (2 MB) -> 2313792
  u16*   xb     = (u16*)  (ws + 2313792);   // 16384*1024 bf16 (32 MB), mode A
  float* out    = (float*)d_out;

  const bool modeA = ws_size >= (size_t)2313792 + 33554432;

  (void)hipMemsetAsync(d_ws, 0, 85568, stream);   // pooled+AWBW+h1pre+cnts
  if (modeA) {
    k01m<true><<<880, 256, 0, stream>>>(x, xb, pooled, Wb, Ao, Bo, Us, Ul,
                                        AWBW, Mbuf, Pb, Wt,
                                        lng, lnb, Wc1, h1pre, Vs, Vl,
                                        bc1, Wc2, bc2, Wrg, brg, Wrc, brc,
                                        Wsg, bsg, Wlc, blc, gates, RwT,
                                        cntS, cntH, cntW);
    k3b_fused<<<512, 256, 0, stream>>>(xb, Wt, Pb, gates, Mbuf, RwT, bb, out);
  } else {
    k01m<false><<<880, 256, 0, stream>>>(x, xb, pooled, Wb, Ao, Bo, Us, Ul,
                                         AWBW, Mbuf, Pb, Wt,
                                         lng, lnb, Wc1, h1pre, Vs, Vl,
                                         bc1, Wc2, bc2, Wrg, brg, Wrc, brc,
                                         Wsg, bsg, Wlc, blc, gates, RwT,
                                         cntS, cntH, cntW);
    k3_fused<false><<<1024, 256, 0, stream>>>(x, xb, Wt, Pb, gates, Mbuf, RwT, bb, out);
  }
}